// Round 1
// 427.838 us; speedup vs baseline: 1.7597x; 1.7597x over previous
//
#include <hip/hip_runtime.h>
#include <math.h>

#define HIDDEN 4096
#define NEXP   128
#define TOPK   8
#define BM     64
#define BKC    64                  // K per staged chunk
#define NCHUNK (HIDDEN / BKC)      // 64
#define SS     132                 // padded stride for score rows in epilogue

// LDS layout (ushort indices). Tiles are [row][k] bf16, row stride 64 ushorts
// = 128 B, XOR-swizzled by ((row&7)<<3) on the ushort index (16B granularity).
#define AH    0                    // A hi   [64][64]
#define AMID  4096                 // A mid
#define ALO   8192                 // A lo
#define BH    12288                // B hi   [128][64]
#define BMID  20480                // B mid
#define BLO   28672                // B lo
#define SMEM_USHORT 36864          // 72 KiB

typedef __attribute__((ext_vector_type(8))) short short8;  // 8 bf16 (4 VGPR)
typedef __attribute__((ext_vector_type(4))) float f32x4;   // MFMA accumulator

struct Split3 { uint4 h, m, l; };

__device__ __forceinline__ unsigned pack2(unsigned a, unsigned b) {
  // low ushort = top16 of a, high ushort = top16 of b
  return (a >> 16) | (b & 0xFFFF0000u);
}

// Triple bf16 split of 8 fp32 values: x = hi + mid + lo + O(2^-26 x).
// hi/mid use round-half-away (bit add 0x8000); residuals are exact (Sterbenz).
__device__ __forceinline__ Split3 split8(float4 a, float4 b) {
  float x[8] = {a.x, a.y, a.z, a.w, b.x, b.y, b.z, b.w};
  unsigned h[8], m[8], l[8];
#pragma unroll
  for (int j = 0; j < 8; ++j) {
    unsigned u  = __float_as_uint(x[j]);
    unsigned hb = (u + 0x8000u) & 0xFFFF0000u;
    float rh    = x[j] - __uint_as_float(hb);
    unsigned um = __float_as_uint(rh);
    unsigned mb = (um + 0x8000u) & 0xFFFF0000u;
    float rm    = rh - __uint_as_float(mb);
    h[j] = hb; m[j] = mb; l[j] = __float_as_uint(rm);  // lo truncated at pack
  }
  Split3 s;
  s.h = make_uint4(pack2(h[0],h[1]), pack2(h[2],h[3]), pack2(h[4],h[5]), pack2(h[6],h[7]));
  s.m = make_uint4(pack2(m[0],m[1]), pack2(m[2],m[3]), pack2(m[4],m[5]), pack2(m[6],m[7]));
  s.l = make_uint4(pack2(l[0],l[1]), pack2(l[2],l[3]), pack2(l[4],l[6]^l[6]^l[6]), 0);
  // (placeholder line replaced below — see corrected assignment)
  s.l = make_uint4(pack2(l[0],l[1]), pack2(l[2],l[3]), pack2(l[4],l[5]), pack2(l[6],l[7]));
  return s;
}

__global__ __launch_bounds__(512, 2) void router_kernel(
    const float* __restrict__ h,     // [T, HIDDEN]
    const float* __restrict__ w,     // [NEXP, HIDDEN]
    const float* __restrict__ bias,  // [NEXP]
    float* __restrict__ out,         // [T*8] indices (as float) then [T*8] weights
    int T)
{
  __shared__ __align__(16) ushort smem_u[SMEM_USHORT];
  const int tid  = threadIdx.x;
  const int row0 = blockIdx.x * BM;

  // wave roles: wn = expert-column tile (32 experts), wk = K-parity half
  const int wid  = tid >> 6;
  const int wn   = wid & 3;
  const int wk   = wid >> 2;
  const int lane = tid & 63;
  const int lrow = lane & 15;   // MFMA row/col index within 16
  const int lk   = lane >> 4;   // MFMA k-group (8 contiguous k)

  // staging coords: each thread owns 8 contiguous k of one row
  const int sr = tid >> 3;      // 0..63
  const int sk = tid & 7;       // 8-elem group along k
  const float* gA  = h + (size_t)(row0 + sr) * HIDDEN + sk * 8;
  const float* gB0 = w + (size_t)sr * HIDDEN + sk * 8;          // experts 0..63
  const float* gB1 = gB0 + (size_t)64 * HIDDEN;                 // experts 64..127

  const int sixA  = (sr * 64 + sk * 8) ^ ((sr & 7) << 3);
  const int rB1   = 64 + sr;
  const int sixB1 = (rB1 * 64 + sk * 8) ^ ((rB1 & 7) << 3);

  f32x4 acc[4][2];
#pragma unroll
  for (int i = 0; i < 4; ++i)
#pragma unroll
    for (int j = 0; j < 2; ++j) acc[i][j] = (f32x4){0.f, 0.f, 0.f, 0.f};

  // prologue: prefetch chunk 0 into registers
  float4 pa0  = *(const float4*)(gA);
  float4 pa1  = *(const float4*)(gA + 4);
  float4 pb00 = *(const float4*)(gB0);
  float4 pb01 = *(const float4*)(gB0 + 4);
  float4 pb10 = *(const float4*)(gB1);
  float4 pb11 = *(const float4*)(gB1 + 4);

  for (int c = 0; c < NCHUNK; ++c) {
    __syncthreads();  // previous chunk's fragment reads complete
    {
      Split3 s = split8(pa0, pa1);
      *(uint4*)(smem_u + AH   + sixA) = s.h;
      *(uint4*)(smem_u + AMID + sixA) = s.m;
      *(uint4*)(smem_u + ALO  + sixA) = s.l;
    }
    {
      Split3 s = split8(pb00, pb01);
      *(uint4*)(smem_u + BH   + sixA) = s.h;   // B rows 0..63: same index expr
      *(uint4*)(smem_u + BMID + sixA) = s.m;
      *(uint4*)(smem_u + BLO  + sixA) = s.l;
    }
    {
      Split3 s = split8(pb10, pb11);
      *(uint4*)(smem_u + BH   + sixB1) = s.h;
      *(uint4*)(smem_u + BMID + sixB1) = s.m;
      *(uint4*)(smem_u + BLO  + sixB1) = s.l;
    }
    if (c + 1 < NCHUNK) {  // prefetch next chunk (hides HBM under compute)
      const int ko = (c + 1) * BKC;
      pa0  = *(const float4*)(gA + ko);
      pa1  = *(const float4*)(gA + ko + 4);
      pb00 = *(const float4*)(gB0 + ko);
      pb01 = *(const float4*)(gB0 + ko + 4);
      pb10 = *(const float4*)(gB1 + ko);
      pb11 = *(const float4*)(gB1 + ko + 4);
    }
    __syncthreads();

    // ---- this wave's K=32 step (wk selects which half of the chunk)
    short8 a_h[4], a_m[4], a_l[4];
#pragma unroll
    for (int mi = 0; mi < 4; ++mi) {
      const int r  = mi * 16 + lrow;
      const int ix = (r * 64 + wk * 32 + lk * 8) ^ ((r & 7) << 3);
      a_h[mi] = *(const short8*)(smem_u + AH   + ix);
      a_m[mi] = *(const short8*)(smem_u + AMID + ix);
      a_l[mi] = *(const short8*)(smem_u + ALO  + ix);
    }
    short8 b_h[2], b_m[2], b_l[2];
#pragma unroll
    for (int ni = 0; ni < 2; ++ni) {
      const int e  = wn * 32 + ni * 16 + lrow;
      const int ix = (e * 64 + wk * 32 + lk * 8) ^ ((e & 7) << 3);
      b_h[ni] = *(const short8*)(smem_u + BH   + ix);
      b_m[ni] = *(const short8*)(smem_u + BMID + ix);
      b_l[ni] = *(const short8*)(smem_u + BLO  + ix);
    }
#pragma unroll
    for (int mi = 0; mi < 4; ++mi)
#pragma unroll
      for (int ni = 0; ni < 2; ++ni) {
        f32x4 cc = acc[mi][ni];
        cc = __builtin_amdgcn_mfma_f32_16x16x32_bf16(a_h[mi], b_h[ni], cc, 0, 0, 0);
        cc = __builtin_amdgcn_mfma_f32_16x16x32_bf16(a_h[mi], b_m[ni], cc, 0, 0, 0);
        cc = __builtin_amdgcn_mfma_f32_16x16x32_bf16(a_m[mi], b_h[ni], cc, 0, 0, 0);
        cc = __builtin_amdgcn_mfma_f32_16x16x32_bf16(a_h[mi], b_l[ni], cc, 0, 0, 0);
        cc = __builtin_amdgcn_mfma_f32_16x16x32_bf16(a_l[mi], b_h[ni], cc, 0, 0, 0);
        cc = __builtin_amdgcn_mfma_f32_16x16x32_bf16(a_m[mi], b_m[ni], cc, 0, 0, 0);
        acc[mi][ni] = cc;
      }
  }

  // ---- combine wave-pair K-partials into score buffer (aliases tiles)
  __syncthreads();
  float* Ss = (float*)smem_u;   // [64][SS]
  if (wk == 1) {
#pragma unroll
    for (int mi = 0; mi < 4; ++mi)
#pragma unroll
      for (int ni = 0; ni < 2; ++ni)
#pragma unroll
        for (int j = 0; j < 4; ++j)
          // D layout (m89): col = lane&15, row = (lane>>4)*4 + j
          Ss[(mi * 16 + lk * 4 + j) * SS + wn * 32 + ni * 16 + lrow] = acc[mi][ni][j];
  }
  __syncthreads();
  if (wk == 0) {
#pragma unroll
    for (int mi = 0; mi < 4; ++mi)
#pragma unroll
      for (int ni = 0; ni < 2; ++ni)
#pragma unroll
        for (int j = 0; j < 4; ++j) {
          const int ixs = (mi * 16 + lk * 4 + j) * SS + wn * 32 + ni * 16 + lrow;
          Ss[ixs] += acc[mi][ni][j];
        }
  }
  __syncthreads();

  // ---- top-k epilogue: wave wid handles tokens wid, wid+8, ... (unchanged logic)
  const float bb0 = bias[lane];
  const float bb1 = bias[lane + 64];

  for (int t = wid; t < BM; t += 8) {
    const float lg0 = Ss[t * SS + lane];
    const float lg1 = Ss[t * SS + 64 + lane];
    const float s0 = 1.0f / (1.0f + expf(-lg0));  // raw sigmoid score
    const float s1 = 1.0f / (1.0f + expf(-lg1));
    float c0 = s0 + bb0;                          // bias-corrected, for selection
    float c1 = s1 + bb1;

    int   sel_i[TOPK];
    float sel_r[TOPK];
    float rsum = 0.0f;
#pragma unroll
    for (int j = 0; j < TOPK; ++j) {
      const bool take0 = (c0 >= c1);
      float v  = take0 ? c0 : c1;
      float rr = take0 ? s0 : s1;
      int   ii = take0 ? lane : lane + 64;
#pragma unroll
      for (int off = 32; off > 0; off >>= 1) {
        const float ov  = __shfl_xor(v, off, 64);
        const float orr = __shfl_xor(rr, off, 64);
        const int   oi  = __shfl_xor(ii, off, 64);
        if (ov > v || (ov == v && oi < ii)) { v = ov; rr = orr; ii = oi; }
      }
      sel_i[j] = ii;
      sel_r[j] = rr;
      rsum += rr;
      if (ii == lane)      c0 = -__builtin_inff();
      if (ii == lane + 64) c1 = -__builtin_inff();
    }
    if (lane == 0) {
      const float inv = 1.0f / (rsum + 1e-20f);
      const size_t tok = (size_t)(row0 + t);
#pragma unroll
      for (int j = 0; j < TOPK; ++j) {
        out[tok * TOPK + j]                    = (float)sel_i[j];
        out[(size_t)T * TOPK + tok * TOPK + j] = sel_r[j] * inv;
      }
    }
  }
}

extern "C" void kernel_launch(void* const* d_in, const int* in_sizes, int n_in,
                              void* d_out, int out_size, void* d_ws, size_t ws_size,
                              hipStream_t stream) {
  const float* h    = (const float*)d_in[0];
  const float* w    = (const float*)d_in[1];
  const float* bias = (const float*)d_in[2];
  float* out = (float*)d_out;
  const int T = in_sizes[0] / HIDDEN;  // 16384

  dim3 grid(T / BM);   // 256 blocks, 1 per CU
  dim3 block(512);     // 8 waves: 4 expert tiles x 2 K-halves
  hipLaunchKernelGGL(router_kernel, grid, block, 0, stream, h, w, bias, out, T);
}